// Round 1
// baseline (4367.265 us; speedup 1.0000x reference)
//
#include <hip/hip_runtime.h>

#define VN 6890
#define RN 5
#define AN 8
#define TN 100
#define NOUT 800   // 8 rotations * 100 templates

// ---------------------------------------------------------------------------
// x0[v,c] = (signal[v,c] - mean[c]) / sqrt(var[c])
__global__ __launch_bounds__(256) void norm_kernel(
    const float* __restrict__ sig, const float* __restrict__ mean,
    const float* __restrict__ var, float* __restrict__ x0)
{
    int i = blockIdx.x * blockDim.x + threadIdx.x;
    if (i < VN * 3) {
        int c = i % 3;
        x0[i] = (sig[i] - mean[c]) / sqrtf(var[c]);
    }
}

// ---------------------------------------------------------------------------
// Fused ISC-Dirac conv: out[v, rot*100+t] = relu( b[t] +
//   sum_{r,a,c} (sum_i bc_w[v,r,a,i]*x[bc_idx[v,r,a,i],c]) * W[t,r,(a+rot)&7,c] )
// GEMM view: C(V x 800) = P(V x 40*CIN) * B(40*CIN x 800), patch gather fused
// into the A-tile build; rotation folded into the B-tile gather index.
// Tiles: BM=64, BN=64, BK=CIN per (r,a) step; 256 threads, 4x4 microtile.
template<int CIN>
__global__ __launch_bounds__(256) void conv_gemm(
    const float* __restrict__ x,      // (VN, CIN)
    const int*   __restrict__ bidx,   // (VN,5,8,3)
    const float* __restrict__ bw,     // (VN,5,8,3)
    const float* __restrict__ W,      // (100,5,8,CIN)
    const float* __restrict__ bias,   // (100)
    float* __restrict__ out)          // (VN,800)
{
    __shared__ __align__(16) float As[CIN][68];   // k-major, pad 68 (16B-aligned rows)
    __shared__ __align__(16) float Bs[CIN][68];
    __shared__ int   sIdx[64][3];
    __shared__ float sW[64][3];

    const int tid = threadIdx.x;
    const int m0 = blockIdx.x * 64;
    const int n0 = blockIdx.y * 64;
    const int tm = tid >> 4;   // 0..15 row group (lanes within 16 share row -> coalesced C writes)
    const int tn = tid & 15;   // 0..15 col group

    float acc[4][4];
    #pragma unroll
    for (int i = 0; i < 4; ++i)
        #pragma unroll
        for (int j = 0; j < 4; ++j) acc[i][j] = 0.f;

    for (int ra = 0; ra < RN * AN; ++ra) {
        const int r = ra >> 3, a = ra & 7;

        // stage barycentric metadata for the 64 vertices of this tile
        if (tid < 192) {
            int m = tid / 3, i = tid - m * 3;
            int v = m0 + m;
            int gi = 0; float gw = 0.f;
            if (v < VN) {
                int o = ((v * RN + r) * AN + a) * 3 + i;
                gi = bidx[o]; gw = bw[o];
            }
            sIdx[m][i] = gi; sW[m][i] = gw;
        }
        __syncthreads();   // meta visible; previous inner-loop reads of As/Bs done

        // A-tile: As[c][m] = sum_i w_i * x[j_i, c]   (coalesced along c)
        for (int e = tid; e < 64 * CIN; e += 256) {
            int m = e / CIN, c = e - m * CIN;
            float v0 = x[sIdx[m][0] * CIN + c];
            float v1 = x[sIdx[m][1] * CIN + c];
            float v2 = x[sIdx[m][2] * CIN + c];
            As[c][m] = sW[m][0] * v0 + sW[m][1] * v1 + sW[m][2] * v2;
        }
        // B-tile: Bs[c][j] = W[t, r, (a+rot)&7, c] for n = n0+j = rot*100+t
        for (int e = tid; e < 64 * CIN; e += 256) {
            int j = e / CIN, c = e - j * CIN;
            int n = n0 + j;
            float val = 0.f;
            if (n < NOUT) {
                int rot = n / TN, t = n - rot * TN;
                int a2 = (a + rot) & 7;
                val = W[((t * RN + r) * AN + a2) * CIN + c];
            }
            Bs[c][j] = val;
        }
        __syncthreads();

        #pragma unroll 4
        for (int k = 0; k < CIN; ++k) {
            float4 av = *reinterpret_cast<const float4*>(&As[k][tm * 4]);
            float4 bv = *reinterpret_cast<const float4*>(&Bs[k][tn * 4]);
            float a4[4] = {av.x, av.y, av.z, av.w};
            float b4[4] = {bv.x, bv.y, bv.z, bv.w};
            #pragma unroll
            for (int i = 0; i < 4; ++i)
                #pragma unroll
                for (int j = 0; j < 4; ++j)
                    acc[i][j] = fmaf(a4[i], b4[j], acc[i][j]);
        }
    }

    // epilogue: + bias[t], relu, store (float4 rows; 800*4B row stride keeps 16B align)
    #pragma unroll
    for (int i = 0; i < 4; ++i) {
        int vr = m0 + tm * 4 + i;
        if (vr >= VN) continue;
        int nb = n0 + tn * 4;
        if (nb + 3 < NOUT) {
            int t = nb % TN;   // nb multiple of 4, 100%4==0 -> t..t+3 same rotation
            float4 o;
            o.x = fmaxf(acc[i][0] + bias[t + 0], 0.f);
            o.y = fmaxf(acc[i][1] + bias[t + 1], 0.f);
            o.z = fmaxf(acc[i][2] + bias[t + 2], 0.f);
            o.w = fmaxf(acc[i][3] + bias[t + 3], 0.f);
            *reinterpret_cast<float4*>(&out[vr * NOUT + nb]) = o;
        } else {
            for (int j = 0; j < 4; ++j) {
                int n = nb + j;
                if (n < NOUT) {
                    int t = n % TN;
                    out[vr * NOUT + n] = fmaxf(acc[i][j] + bias[t], 0.f);
                }
            }
        }
    }
}

// ---------------------------------------------------------------------------
// AngularMaxPooling + BatchNorm. One wave per vertex.
__global__ __launch_bounds__(256) void amp_bn(
    const float* __restrict__ conv,   // (VN, 800) layout [v][rot][t]
    const float* __restrict__ g,  const float* __restrict__ be,
    const float* __restrict__ mu, const float* __restrict__ var,
    float* __restrict__ xout)         // (VN, 100)
{
    int v = blockIdx.x * 4 + (threadIdx.x >> 6);
    int lane = threadIdx.x & 63;
    if (v >= VN) return;
    const float* y = conv + v * NOUT;

    float s[8];
    #pragma unroll
    for (int n = 0; n < 8; ++n) {
        float t1 = y[n * TN + lane];                          // t = lane (0..63)
        float t2 = (lane < 36) ? y[n * TN + 64 + lane] : 0.f; // t = 64+lane (64..99)
        s[n] = t1 * t1 + t2 * t2;
    }
    // butterfly reduce: all lanes end with bitwise-identical sums (fp add commutes)
    #pragma unroll
    for (int off = 32; off > 0; off >>= 1)
        #pragma unroll
        for (int n = 0; n < 8; ++n) s[n] += __shfl_xor(s[n], off);

    int best = 0; float bs = s[0];
    #pragma unroll
    for (int n = 1; n < 8; ++n) { if (s[n] > bs) { bs = s[n]; best = n; } } // first-max = argmax rule

    const float* yb = y + best * TN;
    for (int t = lane; t < TN; t += 64) {
        float inv = 1.0f / sqrtf(var[t] + 1e-3f);
        xout[v * TN + t] = g[t] * (yb[t] - mu[t]) * inv + be[t];
    }
}

// ---------------------------------------------------------------------------
// Dense head: out(V x V) = x(V x 100) @ Dw(100 x V) + db.  K=100 single shot.
__global__ __launch_bounds__(256) void dense_gemm(
    const float* __restrict__ x,    // (VN,100)
    const float* __restrict__ Dw,   // (100,VN)
    const float* __restrict__ db,   // (VN)
    float* __restrict__ out)        // (VN,VN)
{
    __shared__ __align__(16) float As[100][68];
    __shared__ __align__(16) float Bs[100][68];
    const int tid = threadIdx.x;
    const int m0 = blockIdx.x * 64, n0 = blockIdx.y * 64;
    const int tm = tid >> 4, tn = tid & 15;

    for (int e = tid; e < 6400; e += 256) {
        int m = e / 100, k = e - m * 100;
        int v = m0 + m;
        As[k][m] = (v < VN) ? x[v * 100 + k] : 0.f;
    }
    for (int e = tid; e < 6400; e += 256) {
        int k = e >> 6, j = e & 63;
        int n = n0 + j;
        Bs[k][j] = (n < VN) ? Dw[k * VN + n] : 0.f;
    }
    __syncthreads();

    float acc[4][4];
    #pragma unroll
    for (int i = 0; i < 4; ++i)
        #pragma unroll
        for (int j = 0; j < 4; ++j) acc[i][j] = 0.f;

    #pragma unroll 4
    for (int k = 0; k < 100; ++k) {
        float4 av = *reinterpret_cast<const float4*>(&As[k][tm * 4]);
        float4 bv = *reinterpret_cast<const float4*>(&Bs[k][tn * 4]);
        float a4[4] = {av.x, av.y, av.z, av.w};
        float b4[4] = {bv.x, bv.y, bv.z, bv.w};
        #pragma unroll
        for (int i = 0; i < 4; ++i)
            #pragma unroll
            for (int j = 0; j < 4; ++j)
                acc[i][j] = fmaf(a4[i], b4[j], acc[i][j]);
    }

    #pragma unroll
    for (int i = 0; i < 4; ++i) {
        int vr = m0 + tm * 4 + i;
        if (vr >= VN) continue;
        int nb = n0 + tn * 4;
        long base = (long)vr * VN + nb;
        if (nb + 3 < VN) {
            // row stride 6890*4B is 8B-aligned but not 16B -> float2 stores
            float2 o1 = {acc[i][0] + db[nb],     acc[i][1] + db[nb + 1]};
            float2 o2 = {acc[i][2] + db[nb + 2], acc[i][3] + db[nb + 3]};
            *reinterpret_cast<float2*>(&out[base])     = o1;
            *reinterpret_cast<float2*>(&out[base + 2]) = o2;
        } else {
            for (int j = 0; j < 4; ++j) {
                int n = nb + j;
                if (n < VN) out[base + j] = acc[i][j] + db[n];
            }
        }
    }
}

// ---------------------------------------------------------------------------
extern "C" void kernel_launch(void* const* d_in, const int* in_sizes, int n_in,
                              void* d_out, int out_size, void* d_ws, size_t ws_size,
                              hipStream_t stream) {
    const float* signal = (const float*)d_in[0];
    const int*   bcix   = (const int*)  d_in[1];
    const float* bcw    = (const float*)d_in[2];
    const float* nmean  = (const float*)d_in[3];
    const float* nvar   = (const float*)d_in[4];
    const float* w0     = (const float*)d_in[5];
    const float* b0     = (const float*)d_in[6];
    const float* w1     = (const float*)d_in[7];
    const float* b1     = (const float*)d_in[8];
    const float* w2     = (const float*)d_in[9];
    const float* b2     = (const float*)d_in[10];
    const float* bng    = (const float*)d_in[11];
    const float* bnb    = (const float*)d_in[12];
    const float* bnm    = (const float*)d_in[13];
    const float* bnv    = (const float*)d_in[14];
    const float* dw     = (const float*)d_in[15];
    const float* db     = (const float*)d_in[16];
    float* out = (float*)d_out;

    // workspace: x0 (V*3), xA/xB (V*100). conv scratch (V*800 = 22MB) goes in
    // ws when it fits, else borrows d_out (dead before dense_gemm overwrites it).
    float* x0 = (float*)d_ws;
    float* xA = x0 + 20736;      // V*3 = 20670, padded
    float* xB = xA + 689024;     // V*100 = 689000, padded
    size_t need_with_conv = (size_t)(20736 + 2 * 689024 + VN * NOUT) * sizeof(float);
    float* conv = (ws_size >= need_with_conv) ? (xB + 689024) : out;

    dim3 cgrid((VN + 63) / 64, (NOUT + 63) / 64);   // 108 x 13
    dim3 dgrid((VN + 63) / 64, (VN + 63) / 64);     // 108 x 108
    int ampg = (VN + 3) / 4;                         // 1723

    norm_kernel<<<(VN * 3 + 255) / 256, 256, 0, stream>>>(signal, nmean, nvar, x0);

    conv_gemm<3><<<cgrid, 256, 0, stream>>>(x0, bcix, bcw, w0, b0, conv);
    amp_bn<<<ampg, 256, 0, stream>>>(conv, bng, bnb, bnm, bnv, xA);

    conv_gemm<100><<<cgrid, 256, 0, stream>>>(xA, bcix, bcw, w1, b1, conv);
    amp_bn<<<ampg, 256, 0, stream>>>(conv, bng + 100, bnb + 100, bnm + 100, bnv + 100, xB);

    conv_gemm<100><<<cgrid, 256, 0, stream>>>(xB, bcix, bcw, w2, b2, conv);
    amp_bn<<<ampg, 256, 0, stream>>>(conv, bng + 200, bnb + 200, bnm + 200, bnv + 200, xA);

    dense_gemm<<<dgrid, 256, 0, stream>>>(xA, dw, db, out);
}

// Round 2
// 2002.253 us; speedup vs baseline: 2.1812x; 2.1812x over previous
//
#include <hip/hip_runtime.h>

#define VN 6890
#define TN 100
#define NOUT 800   // 8 rotations * 100 templates

// ---------------------------------------------------------------------------
// x0[v,c] = (signal[v,c] - mean[c]) / sqrt(var[c])
__global__ __launch_bounds__(256) void norm_kernel(
    const float* __restrict__ sig, const float* __restrict__ mean,
    const float* __restrict__ var, float* __restrict__ x0)
{
    int i = blockIdx.x * blockDim.x + threadIdx.x;
    if (i < VN * 3) {
        int c = i % 3;
        x0[i] = (sig[i] - mean[c]) / sqrtf(var[c]);
    }
}

// ---------------------------------------------------------------------------
// Materialize rotated weight matrix: Brot[k][n] = W[t, r, (a+rot)&7, c]
// k = (r*8+a)*CIN + c  (matches patch layout), n = rot*100 + t.
template<int CIN>
__global__ __launch_bounds__(256) void rotw_kernel(
    const float* __restrict__ W, float* __restrict__ Brot)
{
    int k = blockIdx.x;                 // 0 .. 40*CIN-1
    int ra = k / CIN, c = k - ra * CIN;
    int r = ra >> 3, a = ra & 7;
    for (int n = threadIdx.x; n < NOUT; n += 256) {
        int rot = n / TN, t = n - rot * TN;
        int a2 = (a + rot) & 7;
        Brot[(size_t)k * NOUT + n] = W[((t * 5 + r) * 8 + a2) * CIN + c];
    }
}

// ---------------------------------------------------------------------------
// Materialize barycentric patch: P[v][ra*CIN+c] = sum_i bw_i * x[idx_i][c]
template<int CIN>
__global__ __launch_bounds__(256) void patch_kernel(
    const float* __restrict__ x, const int* __restrict__ bidx,
    const float* __restrict__ bw, float* __restrict__ P)
{
    __shared__ int   sIdx[120];
    __shared__ float sW[120];
    const int v = blockIdx.x;
    const int tid = threadIdx.x;
    if (tid < 120) { sIdx[tid] = bidx[v * 120 + tid]; sW[tid] = bw[v * 120 + tid]; }
    __syncthreads();
    const int K = 40 * CIN;
    for (int e = tid; e < K; e += 256) {
        int ra = e / CIN, c = e - ra * CIN;
        float s = sW[ra * 3 + 0] * x[sIdx[ra * 3 + 0] * CIN + c]
                + sW[ra * 3 + 1] * x[sIdx[ra * 3 + 1] * CIN + c]
                + sW[ra * 3 + 2] * x[sIdx[ra * 3 + 2] * CIN + c];
        P[(size_t)v * K + e] = s;
    }
}

// ---------------------------------------------------------------------------
// fp32 SGEMM: C(MxN) = A(MxK) @ B(KxN) + bias, optional relu.
// BM=128, BN=64, BK=32, 256 threads, 8x4 microtile, register-prefetch pipeline.
// CONV_EPI: bias[t = n%100] + relu, float4 stores (N=800).
// else:     bias[n], no relu, float2 stores (N may be %4 != 0).
// Requires K % 4 == 0.
template<bool CONV_EPI>
__global__ __launch_bounds__(256, 4) void tile_gemm(
    const float* __restrict__ A, const float* __restrict__ B,
    const float* __restrict__ bias, float* __restrict__ C,
    int M, int N, int K)
{
    __shared__ __align__(16) float As[32][132];  // k-major, 132*4B row (16B aligned)
    __shared__ __align__(16) float Bs[32][68];

    const int tid = threadIdx.x;
    const int m0 = blockIdx.x * 128;
    const int n0 = blockIdx.y * 64;
    const int ty = tid >> 4;    // 0..15 -> rows ty*8 .. ty*8+7
    const int tx = tid & 15;    // 0..15 -> cols tx*4 .. tx*4+3
    const int nkt = (K + 31) >> 5;

    float4 aR[4];
    float2 bR[4];

    auto load_tile = [&](int kt) {
        const int k0 = kt << 5;
        #pragma unroll
        for (int j = 0; j < 4; ++j) {
            int q = tid + 256 * j;                   // 0..1023
            int row = q >> 3, kq = (q & 7) << 2;
            int v = m0 + row, k = k0 + kq;
            if (v < M && k < K)
                aR[j] = *reinterpret_cast<const float4*>(A + (size_t)v * K + k);
            else
                aR[j] = make_float4(0.f, 0.f, 0.f, 0.f);
        }
        #pragma unroll
        for (int j = 0; j < 2; ++j) {
            int q = tid + 256 * j;                   // 0..511
            int krow = q >> 4, nq = (q & 15) << 2;
            int k = k0 + krow, n = n0 + nq;
            bR[2 * j]     = (k < K && n + 1 < N)
                ? *reinterpret_cast<const float2*>(B + (size_t)k * N + n)     : make_float2(0.f, 0.f);
            bR[2 * j + 1] = (k < K && n + 3 < N)
                ? *reinterpret_cast<const float2*>(B + (size_t)k * N + n + 2) : make_float2(0.f, 0.f);
        }
    };
    auto stage = [&]() {
        #pragma unroll
        for (int j = 0; j < 4; ++j) {
            int q = tid + 256 * j;
            int row = q >> 3, kq = (q & 7) << 2;
            As[kq + 0][row] = aR[j].x; As[kq + 1][row] = aR[j].y;
            As[kq + 2][row] = aR[j].z; As[kq + 3][row] = aR[j].w;
        }
        #pragma unroll
        for (int j = 0; j < 2; ++j) {
            int q = tid + 256 * j;
            int krow = q >> 4, nq = (q & 15) << 2;
            *reinterpret_cast<float2*>(&Bs[krow][nq])     = bR[2 * j];
            *reinterpret_cast<float2*>(&Bs[krow][nq + 2]) = bR[2 * j + 1];
        }
    };

    float acc[8][4];
    #pragma unroll
    for (int i = 0; i < 8; ++i)
        #pragma unroll
        for (int j = 0; j < 4; ++j) acc[i][j] = 0.f;

    load_tile(0);
    stage();
    __syncthreads();

    for (int kt = 0; kt < nkt; ++kt) {
        if (kt + 1 < nkt) load_tile(kt + 1);   // global loads overlap compute
        #pragma unroll 16
        for (int k = 0; k < 32; ++k) {
            float4 a0 = *reinterpret_cast<const float4*>(&As[k][ty * 8]);
            float4 a1 = *reinterpret_cast<const float4*>(&As[k][ty * 8 + 4]);
            float4 b  = *reinterpret_cast<const float4*>(&Bs[k][tx * 4]);
            float av[8] = {a0.x, a0.y, a0.z, a0.w, a1.x, a1.y, a1.z, a1.w};
            float bv[4] = {b.x, b.y, b.z, b.w};
            #pragma unroll
            for (int i = 0; i < 8; ++i)
                #pragma unroll
                for (int j = 0; j < 4; ++j)
                    acc[i][j] = fmaf(av[i], bv[j], acc[i][j]);
        }
        __syncthreads();
        if (kt + 1 < nkt) { stage(); __syncthreads(); }
    }

    // epilogue
    #pragma unroll
    for (int i = 0; i < 8; ++i) {
        int vr = m0 + ty * 8 + i;
        if (vr >= M) continue;
        int nb = n0 + tx * 4;
        size_t base = (size_t)vr * N + nb;
        if (CONV_EPI) {
            if (nb < N) {                 // N%4==0 -> full float4
                int t = nb % TN;          // nb%4==0, 100%4==0 -> same rotation
                float4 o;
                o.x = fmaxf(acc[i][0] + bias[t + 0], 0.f);
                o.y = fmaxf(acc[i][1] + bias[t + 1], 0.f);
                o.z = fmaxf(acc[i][2] + bias[t + 2], 0.f);
                o.w = fmaxf(acc[i][3] + bias[t + 3], 0.f);
                *reinterpret_cast<float4*>(C + base) = o;
            }
        } else {
            if (nb + 1 < N) {
                float2 o = {acc[i][0] + bias[nb], acc[i][1] + bias[nb + 1]};
                *reinterpret_cast<float2*>(C + base) = o;
            }
            if (nb + 3 < N) {
                float2 o = {acc[i][2] + bias[nb + 2], acc[i][3] + bias[nb + 3]};
                *reinterpret_cast<float2*>(C + base + 2) = o;
            }
        }
    }
}

// ---------------------------------------------------------------------------
// AngularMaxPooling + BatchNorm. One wave per vertex.
__global__ __launch_bounds__(256) void amp_bn(
    const float* __restrict__ conv,   // (VN, 800) layout [v][rot][t]
    const float* __restrict__ g,  const float* __restrict__ be,
    const float* __restrict__ mu, const float* __restrict__ var,
    float* __restrict__ xout)         // (VN, 100)
{
    int v = blockIdx.x * 4 + (threadIdx.x >> 6);
    int lane = threadIdx.x & 63;
    if (v >= VN) return;
    const float* y = conv + (size_t)v * NOUT;

    float s[8];
    #pragma unroll
    for (int n = 0; n < 8; ++n) {
        float t1 = y[n * TN + lane];
        float t2 = (lane < 36) ? y[n * TN + 64 + lane] : 0.f;
        s[n] = t1 * t1 + t2 * t2;
    }
    #pragma unroll
    for (int off = 32; off > 0; off >>= 1)
        #pragma unroll
        for (int n = 0; n < 8; ++n) s[n] += __shfl_xor(s[n], off);

    int best = 0; float bs = s[0];
    #pragma unroll
    for (int n = 1; n < 8; ++n) { if (s[n] > bs) { bs = s[n]; best = n; } }

    const float* yb = y + best * TN;
    for (int t = lane; t < TN; t += 64) {
        float inv = 1.0f / sqrtf(var[t] + 1e-3f);
        xout[v * TN + t] = g[t] * (yb[t] - mu[t]) * inv + be[t];
    }
}

// ---------------------------------------------------------------------------
extern "C" void kernel_launch(void* const* d_in, const int* in_sizes, int n_in,
                              void* d_out, int out_size, void* d_ws, size_t ws_size,
                              hipStream_t stream) {
    const float* signal = (const float*)d_in[0];
    const int*   bcix   = (const int*)  d_in[1];
    const float* bcw    = (const float*)d_in[2];
    const float* nmean  = (const float*)d_in[3];
    const float* nvar   = (const float*)d_in[4];
    const float* w0     = (const float*)d_in[5];
    const float* b0     = (const float*)d_in[6];
    const float* w1     = (const float*)d_in[7];
    const float* b1     = (const float*)d_in[8];
    const float* w2     = (const float*)d_in[9];
    const float* b2     = (const float*)d_in[10];
    const float* bng    = (const float*)d_in[11];
    const float* bnb    = (const float*)d_in[12];
    const float* bnm    = (const float*)d_in[13];
    const float* bnv    = (const float*)d_in[14];
    const float* dw     = (const float*)d_in[15];
    const float* db     = (const float*)d_in[16];
    float* out = (float*)d_out;

    // Small activations in ws (round-1 proved ws >= 5.6MB).
    float* x0 = (float*)d_ws;
    float* xA = x0 + 20736;       // V*3 padded
    float* xB = xA + 689024;      // V*100 padded

    // Big scratch lives in d_out (V*V = 47.47M floats = 190MB), dead until dense:
    float* P    = out;                      // 6890*4000      = 27,560,000 floats
    float* conv = out + 27560000;           // 6890*800       =  5,512,000
    float* Brot = out + 27560000 + 5512000; // 4000*800       =  3,200,000  (tot 36.3M < 47.4M)

    dim3 cgrid((VN + 127) / 128, (NOUT + 63) / 64);   // 54 x 13
    dim3 dgrid((VN + 127) / 128, (VN + 63) / 64);     // 54 x 108
    int ampg = (VN + 3) / 4;

    norm_kernel<<<(VN * 3 + 255) / 256, 256, 0, stream>>>(signal, nmean, nvar, x0);

    // layer 0 (CIN=3, K=120)
    rotw_kernel<3><<<120, 256, 0, stream>>>(w0, Brot);
    patch_kernel<3><<<VN, 256, 0, stream>>>(x0, bcix, bcw, P);
    tile_gemm<true><<<cgrid, 256, 0, stream>>>(P, Brot, b0, conv, VN, NOUT, 120);
    amp_bn<<<ampg, 256, 0, stream>>>(conv, bng, bnb, bnm, bnv, xA);

    // layer 1 (CIN=100, K=4000)
    rotw_kernel<100><<<4000, 256, 0, stream>>>(w1, Brot);
    patch_kernel<100><<<VN, 256, 0, stream>>>(xA, bcix, bcw, P);
    tile_gemm<true><<<cgrid, 256, 0, stream>>>(P, Brot, b1, conv, VN, NOUT, 4000);
    amp_bn<<<ampg, 256, 0, stream>>>(conv, bng + 100, bnb + 100, bnm + 100, bnv + 100, xB);

    // layer 2 (CIN=100, K=4000)
    rotw_kernel<100><<<4000, 256, 0, stream>>>(w2, Brot);
    patch_kernel<100><<<VN, 256, 0, stream>>>(xB, bcix, bcw, P);
    tile_gemm<true><<<cgrid, 256, 0, stream>>>(P, Brot, b2, conv, VN, NOUT, 4000);
    amp_bn<<<ampg, 256, 0, stream>>>(conv, bng + 200, bnb + 200, bnm + 200, bnv + 200, xA);

    // dense head (K=100, N=V)
    tile_gemm<false><<<dgrid, 256, 0, stream>>>(xA, dw, db, out, VN, VN, 100);
}